// Round 11
// baseline (125.022 us; speedup 1.0000x reference)
//
#include <hip/hip_runtime.h>
#include <math.h>

// FutureEncoder: B=4, S=2048, D=1024, FUTURE_K=32, fp32 in/out.
// R14: fused, G=32 tokens/block (R13 falsified the latency theory: time
// scales with staged bytes -> cut per-token staging redundancy 3.06x->2.03x).
// 256 blocks x 512 thr. Scores: 8 waves = token-half x 256-wide D-slice,
// proven R10 MFMA body. Softmax: 32 tokens x 16 thr, weights -> LDS by
// future-offset q. PV: 8 waves x 4 tokens, constant 35-row window, branchless.

constexpr int S_CONST = 2048;
constexpr int D = 1024;
constexpr int G = 32;            // tokens per block
constexpr int NTOK = 8192;
constexpr int JP = 49;           // padded stride for score partials
constexpr int WQ = 33;           // padded stride for weight LDS

typedef short bf16x8 __attribute__((ext_vector_type(8)));
typedef float f32x4  __attribute__((ext_vector_type(4)));
typedef unsigned int u32x4 __attribute__((ext_vector_type(4)));

// 8 fp32 -> hi/lo bf16 fragments via v_cvt_pk_bf16_f32 (RNE).
__device__ inline void cvt8(float4 x0, float4 x1, bf16x8& hi, bf16x8& lo) {
    float xs[8] = {x0.x, x0.y, x0.z, x0.w, x1.x, x1.y, x1.z, x1.w};
    u32x4 hv, lv;
    #pragma unroll
    for (int p = 0; p < 4; ++p) {
        float a = xs[2 * p], b = xs[2 * p + 1];
        unsigned hp;
        asm("v_cvt_pk_bf16_f32 %0, %1, %2" : "=v"(hp) : "v"(a), "v"(b));
        float ha = __builtin_bit_cast(float, hp << 16);
        float hb = __builtin_bit_cast(float, hp & 0xffff0000u);
        float la = a - ha, lb = b - hb;
        unsigned lp;
        asm("v_cvt_pk_bf16_f32 %0, %1, %2" : "=v"(lp) : "v"(la), "v"(lb));
        hv[p] = hp; lv[p] = lp;
    }
    hi = __builtin_bit_cast(bf16x8, hv);
    lo = __builtin_bit_cast(bf16x8, lv);
}

__global__ __launch_bounds__(512)
void future_encoder_kernel(const float* __restrict__ h,
                           float* __restrict__ out) {
    __shared__ float sc[8 * 16 * JP];  // [wave][m][j] partial scores (~25 KB)
    __shared__ float wm[G * WQ];       // [token][q] softmax weights

    // XCD swizzle: contiguous chunk per XCD (256 blocks / 8 XCDs)
    int bid = blockIdx.x, nblk = gridDim.x, lb = bid;
    if ((nblk & 7) == 0) {
        int per = nblk >> 3;
        lb = (bid & 7) * per + (bid >> 3);
    }

    const int tid  = threadIdx.x;
    const int w    = tid >> 6;
    const int lane = tid & 63;
    const int t0   = lb * G;                    // first token of block

    // ---------------- Phase 1: scores via MFMA -------------------------------
    // wave w: token-half th = w>>2 (16 tokens at t0+16*th), D-slice ds = w&3.
    {
        const int th   = w >> 2;
        const int ds   = w & 3;
        const int d0   = ds * 256;
        const int mrow = lane & 15;
        const int q8   = (lane >> 4) * 8;
        const int tb   = t0 + 16 * th;

        const float* A = h + (size_t)(tb + mrow) * D + d0 + q8;   // tb+15 <= 8191
        int r0 = min(tb +  1 + mrow, NTOK - 1);
        int r1 = min(tb + 17 + mrow, NTOK - 1);
        int r2 = min(tb + 33 + mrow, NTOK - 1);
        const float* B0 = h + (size_t)r0 * D + d0 + q8;
        const float* B1 = h + (size_t)r1 * D + d0 + q8;
        const float* B2 = h + (size_t)r2 * D + d0 + q8;

        f32x4 acc[3] = {{0,0,0,0},{0,0,0,0},{0,0,0,0}};

        float4 xa0 = *(const float4*)(A),  xa1 = *(const float4*)(A + 4);
        float4 x00 = *(const float4*)(B0), x01 = *(const float4*)(B0 + 4);
        float4 x10 = *(const float4*)(B1), x11 = *(const float4*)(B1 + 4);
        float4 x20 = *(const float4*)(B2), x21 = *(const float4*)(B2 + 4);

        #pragma unroll
        for (int kk = 0; kk < 8; ++kk) {
            float4 na0, na1, n00, n01, n10, n11, n20, n21;
            if (kk < 7) {
                const int o = (kk + 1) * 32;
                na0 = *(const float4*)(A  + o); na1 = *(const float4*)(A  + o + 4);
                n00 = *(const float4*)(B0 + o); n01 = *(const float4*)(B0 + o + 4);
                n10 = *(const float4*)(B1 + o); n11 = *(const float4*)(B1 + o + 4);
                n20 = *(const float4*)(B2 + o); n21 = *(const float4*)(B2 + o + 4);
            }

            bf16x8 ah, al, bh, bl;
            cvt8(xa0, xa1, ah, al);

            cvt8(x00, x01, bh, bl);
            acc[0] = __builtin_amdgcn_mfma_f32_16x16x32_bf16(ah, bh, acc[0], 0, 0, 0);
            acc[0] = __builtin_amdgcn_mfma_f32_16x16x32_bf16(ah, bl, acc[0], 0, 0, 0);
            acc[0] = __builtin_amdgcn_mfma_f32_16x16x32_bf16(al, bh, acc[0], 0, 0, 0);

            cvt8(x10, x11, bh, bl);
            acc[1] = __builtin_amdgcn_mfma_f32_16x16x32_bf16(ah, bh, acc[1], 0, 0, 0);
            acc[1] = __builtin_amdgcn_mfma_f32_16x16x32_bf16(ah, bl, acc[1], 0, 0, 0);
            acc[1] = __builtin_amdgcn_mfma_f32_16x16x32_bf16(al, bh, acc[1], 0, 0, 0);

            cvt8(x20, x21, bh, bl);
            acc[2] = __builtin_amdgcn_mfma_f32_16x16x32_bf16(ah, bh, acc[2], 0, 0, 0);
            acc[2] = __builtin_amdgcn_mfma_f32_16x16x32_bf16(ah, bl, acc[2], 0, 0, 0);
            acc[2] = __builtin_amdgcn_mfma_f32_16x16x32_bf16(al, bh, acc[2], 0, 0, 0);

            if (kk < 7) {
                xa0 = na0; xa1 = na1;
                x00 = n00; x01 = n01;
                x10 = n10; x11 = n11;
                x20 = n20; x21 = n21;
            }
        }

        // C layout: col = lane&15 (j within tile), row = (lane>>4)*4 + reg
        #pragma unroll
        for (int t = 0; t < 3; ++t) {
            #pragma unroll
            for (int r = 0; r < 4; ++r) {
                int m = (lane >> 4) * 4 + r;
                int j = t * 16 + (lane & 15);
                sc[(w * 16 + m) * JP + j] = acc[t][r];
            }
        }
    }
    __syncthreads();

    // ---------------- Phase 1.5: reduce 4 D-slices + softmax -> wm -----------
    {
        const int i   = tid >> 4;      // token 0..31
        const int sub = tid & 15;      // 16 threads per token
        const int th2 = i >> 4;
        const int m   = i & 15;
        const int sb  = (t0 + 16 * th2) & (S_CONST - 1);
        const int jl  = (S_CONST - 2) - sb;     // max valid j for this half

        float v[3];
        #pragma unroll
        for (int c = 0; c < 3; ++c) {
            int j = sub + c * 16;
            float s = sc[((th2 * 4 + 0) * 16 + m) * JP + j]
                    + sc[((th2 * 4 + 1) * 16 + m) * JP + j]
                    + sc[((th2 * 4 + 2) * 16 + m) * JP + j]
                    + sc[((th2 * 4 + 3) * 16 + m) * JP + j];
            bool valid = (j >= m) && (j <= m + 31) && (j <= jl);
            v[c] = valid ? s : -1e9f;
        }
        float mx = fmaxf(v[0], fmaxf(v[1], v[2]));
        #pragma unroll
        for (int d = 1; d < 16; d <<= 1) mx = fmaxf(mx, __shfl_xor(mx, d, 16));

        float e[3];
        float sum = 0.f;
        #pragma unroll
        for (int c = 0; c < 3; ++c) { e[c] = __expf(v[c] - mx); sum += e[c]; }
        #pragma unroll
        for (int d = 1; d < 16; d <<= 1) sum += __shfl_xor(sum, d, 16);

        const bool any = (mx > -5e8f);
        const float inv = any ? (1.0f / sum) : 0.f;

        #pragma unroll
        for (int c = 0; c < 3; ++c) {
            int j = sub + c * 16;
            int q = j - m;                       // future offset 0..31
            bool valid = (j >= m) && (j <= m + 31) && (j <= jl);
            if (q >= 0 && q < 32)
                wm[i * WQ + q] = valid ? e[c] * inv : 0.f;
        }
    }
    __syncthreads();

    // ---------------- Phase 2: PV fp32 VALU; wave w -> tokens w*4..w*4+3 -----
    {
        const int i0   = w * 4;
        const int doff = lane * 4;

        float4 a0[4] = {}, a1[4] = {}, a2[4] = {}, a3[4] = {};

        for (int rr = 0; rr <= 34; ++rr) {
            int r = min(t0 + 1 + i0 + rr, NTOK - 1);
            const float* fp = h + (size_t)r * D + doff;
            // token i0+t sees future-offset q = rr - t; invalid -> weight 0
            const float w0 = (rr <= 31)            ? wm[(i0 + 0) * WQ + rr]     : 0.f;
            const float w1 = (rr >= 1 && rr <= 32) ? wm[(i0 + 1) * WQ + rr - 1] : 0.f;
            const float w2 = (rr >= 2 && rr <= 33) ? wm[(i0 + 2) * WQ + rr - 2] : 0.f;
            const float w3 = (rr >= 3)             ? wm[(i0 + 3) * WQ + rr - 3] : 0.f;
            #pragma unroll
            for (int c = 0; c < 4; ++c) {
                float4 f = *(const float4*)(fp + c * 256);
                a0[c].x += w0 * f.x; a0[c].y += w0 * f.y; a0[c].z += w0 * f.z; a0[c].w += w0 * f.w;
                a1[c].x += w1 * f.x; a1[c].y += w1 * f.y; a1[c].z += w1 * f.z; a1[c].w += w1 * f.w;
                a2[c].x += w2 * f.x; a2[c].y += w2 * f.y; a2[c].z += w2 * f.z; a2[c].w += w2 * f.w;
                a3[c].x += w3 * f.x; a3[c].y += w3 * f.y; a3[c].z += w3 * f.z; a3[c].w += w3 * f.w;
            }
        }

        float* o0 = out + (size_t)(t0 + i0) * D + doff;
        #pragma unroll
        for (int c = 0; c < 4; ++c) *(float4*)(o0 + 0 * D + c * 256) = a0[c];
        #pragma unroll
        for (int c = 0; c < 4; ++c) *(float4*)(o0 + 1 * D + c * 256) = a1[c];
        #pragma unroll
        for (int c = 0; c < 4; ++c) *(float4*)(o0 + 2 * D + c * 256) = a2[c];
        #pragma unroll
        for (int c = 0; c < 4; ++c) *(float4*)(o0 + 3 * D + c * 256) = a3[c];
    }
}

extern "C" void kernel_launch(void* const* d_in, const int* in_sizes, int n_in,
                              void* d_out, int out_size, void* d_ws, size_t ws_size,
                              hipStream_t stream) {
    const float* h = (const float*)d_in[0];
    float* out = (float*)d_out;
    const int ntok = in_sizes[0] / D;        // 8192
    const int blocks = ntok / G;             // 256
    future_encoder_kernel<<<blocks, 512, 0, stream>>>(h, out);
}

// Round 12
// 107.753 us; speedup vs baseline: 1.1603x; 1.1603x over previous
//
#include <hip/hip_runtime.h>
#include <math.h>

// FutureEncoder: B=4, S=2048, D=1024, FUTURE_K=32, fp32 in/out.
// R15: double grid parallelism at CONSTANT staged bytes (R13: more blocks via
// fewer tokens = +65% bytes = worse; R14: fewer blocks = spills = worse).
//   Kernel A: partial scores, grid = (512 token-groups x 2 D-halves) = 1024
//             blocks, 4 waves x 128-wide D-slice, proven MFMA body, raw
//             partials [2][8192][48] -> workspace.
//   Kernel B: softmax (sum halves + mask + shuffle reduce) fused with the
//             proven TB=8 streaming PV body. 1024 blocks.

constexpr int S_CONST = 2048;
constexpr int D = 1024;
constexpr int G = 16;            // tokens per scores-group
constexpr int NTOK = 8192;
constexpr int JP = 49;           // padded stride for score LDS
constexpr int TB = 8;            // tokens per PV-block

typedef short bf16x8 __attribute__((ext_vector_type(8)));
typedef float f32x4  __attribute__((ext_vector_type(4)));
typedef unsigned int u32x4 __attribute__((ext_vector_type(4)));

// 8 fp32 -> hi/lo bf16 fragments via v_cvt_pk_bf16_f32 (RNE).
__device__ inline void cvt8(float4 x0, float4 x1, bf16x8& hi, bf16x8& lo) {
    float xs[8] = {x0.x, x0.y, x0.z, x0.w, x1.x, x1.y, x1.z, x1.w};
    u32x4 hv, lv;
    #pragma unroll
    for (int p = 0; p < 4; ++p) {
        float a = xs[2 * p], b = xs[2 * p + 1];
        unsigned hp;
        asm("v_cvt_pk_bf16_f32 %0, %1, %2" : "=v"(hp) : "v"(a), "v"(b));
        float ha = __builtin_bit_cast(float, hp << 16);
        float hb = __builtin_bit_cast(float, hp & 0xffff0000u);
        float la = a - ha, lb = b - hb;
        unsigned lp;
        asm("v_cvt_pk_bf16_f32 %0, %1, %2" : "=v"(lp) : "v"(la), "v"(lb));
        hv[p] = hp; lv[p] = lp;
    }
    hi = __builtin_bit_cast(bf16x8, hv);
    lo = __builtin_bit_cast(bf16x8, lv);
}

// ---------------------------------------------------------------------------
// Kernel A: partial scores for one D-half.
// block = (token-group tg, D-half dh). 256 thr = 4 waves x 128-wide slice.
// Writes raw partials ps[dh][tok][48] (no masking here).
// ---------------------------------------------------------------------------
__global__ __launch_bounds__(256)
void scores_kernel(const float* __restrict__ h, float* __restrict__ ps) {
    __shared__ float sc[4 * G * JP];   // [wave][m][j]

    int bid = blockIdx.x, nblk = gridDim.x, lb = bid;
    if ((nblk & 7) == 0) {
        int per = nblk >> 3;
        lb = (bid & 7) * per + (bid >> 3);
    }
    const int tg = lb & 511;           // token group 0..511
    const int dh = lb >> 9;            // D-half 0..1

    const int tid  = threadIdx.x;
    const int w    = tid >> 6;
    const int lane = tid & 63;
    const int t0   = tg * G;

    // ---------------- partial scores via MFMA (128-wide slice per wave) -----
    {
        const int d0   = dh * 512 + w * 128;
        const int mrow = lane & 15;
        const int q8   = (lane >> 4) * 8;

        const float* A = h + (size_t)(t0 + mrow) * D + d0 + q8;
        int r0 = min(t0 +  1 + mrow, NTOK - 1);
        int r1 = min(t0 + 17 + mrow, NTOK - 1);
        int r2 = min(t0 + 33 + mrow, NTOK - 1);
        const float* B0 = h + (size_t)r0 * D + d0 + q8;
        const float* B1 = h + (size_t)r1 * D + d0 + q8;
        const float* B2 = h + (size_t)r2 * D + d0 + q8;

        f32x4 acc[3] = {{0,0,0,0},{0,0,0,0},{0,0,0,0}};

        float4 xa0 = *(const float4*)(A),  xa1 = *(const float4*)(A + 4);
        float4 x00 = *(const float4*)(B0), x01 = *(const float4*)(B0 + 4);
        float4 x10 = *(const float4*)(B1), x11 = *(const float4*)(B1 + 4);
        float4 x20 = *(const float4*)(B2), x21 = *(const float4*)(B2 + 4);

        #pragma unroll
        for (int kk = 0; kk < 4; ++kk) {
            float4 na0, na1, n00, n01, n10, n11, n20, n21;
            if (kk < 3) {
                const int o = (kk + 1) * 32;
                na0 = *(const float4*)(A  + o); na1 = *(const float4*)(A  + o + 4);
                n00 = *(const float4*)(B0 + o); n01 = *(const float4*)(B0 + o + 4);
                n10 = *(const float4*)(B1 + o); n11 = *(const float4*)(B1 + o + 4);
                n20 = *(const float4*)(B2 + o); n21 = *(const float4*)(B2 + o + 4);
            }

            bf16x8 ah, al, bh, bl;
            cvt8(xa0, xa1, ah, al);

            cvt8(x00, x01, bh, bl);
            acc[0] = __builtin_amdgcn_mfma_f32_16x16x32_bf16(ah, bh, acc[0], 0, 0, 0);
            acc[0] = __builtin_amdgcn_mfma_f32_16x16x32_bf16(ah, bl, acc[0], 0, 0, 0);
            acc[0] = __builtin_amdgcn_mfma_f32_16x16x32_bf16(al, bh, acc[0], 0, 0, 0);

            cvt8(x10, x11, bh, bl);
            acc[1] = __builtin_amdgcn_mfma_f32_16x16x32_bf16(ah, bh, acc[1], 0, 0, 0);
            acc[1] = __builtin_amdgcn_mfma_f32_16x16x32_bf16(ah, bl, acc[1], 0, 0, 0);
            acc[1] = __builtin_amdgcn_mfma_f32_16x16x32_bf16(al, bh, acc[1], 0, 0, 0);

            cvt8(x20, x21, bh, bl);
            acc[2] = __builtin_amdgcn_mfma_f32_16x16x32_bf16(ah, bh, acc[2], 0, 0, 0);
            acc[2] = __builtin_amdgcn_mfma_f32_16x16x32_bf16(ah, bl, acc[2], 0, 0, 0);
            acc[2] = __builtin_amdgcn_mfma_f32_16x16x32_bf16(al, bh, acc[2], 0, 0, 0);

            if (kk < 3) {
                xa0 = na0; xa1 = na1;
                x00 = n00; x01 = n01;
                x10 = n10; x11 = n11;
                x20 = n20; x21 = n21;
            }
        }

        // C layout: col = lane&15 (j within tile), row = (lane>>4)*4 + reg
        #pragma unroll
        for (int t = 0; t < 3; ++t) {
            #pragma unroll
            for (int r = 0; r < 4; ++r) {
                int m = (lane >> 4) * 4 + r;
                int j = t * 16 + (lane & 15);
                sc[(w * G + m) * JP + j] = acc[t][r];
            }
        }
    }
    __syncthreads();

    // ---------------- reduce 4 slice-partials -> global ps[dh][tok][48] -----
    {
        const int i   = tid >> 4;      // token 0..15
        const int sub = tid & 15;
        float* prow = ps + ((size_t)dh * NTOK + t0 + i) * 48;
        #pragma unroll
        for (int c = 0; c < 3; ++c) {
            int j = sub + c * 16;
            float s = sc[(0 * G + i) * JP + j] + sc[(1 * G + i) * JP + j]
                    + sc[(2 * G + i) * JP + j] + sc[(3 * G + i) * JP + j];
            prow[j] = s;
        }
    }
}

// ---------------------------------------------------------------------------
// Kernel B: softmax (sum D-halves, mask, reduce) + streaming PV.
// Block = 8 tokens, 256 threads. PV: 39-row static sliding window.
// ---------------------------------------------------------------------------
__global__ __launch_bounds__(256)
void pv_kernel(const float* __restrict__ h, const float* __restrict__ ps,
               float* __restrict__ out) {
    __shared__ float wm[TB * 32];      // 8 tokens x 32 weights (by q-offset)

    int bid = blockIdx.x, nblk = gridDim.x, lb = bid;
    if ((nblk & 7) == 0) {
        int per = nblk >> 3;
        lb = (bid & 7) * per + (bid >> 3);
    }
    const int i0   = lb * TB;
    const int tid  = threadIdx.x;

    // ---- softmax for the block's 8 tokens (128 threads: 16 per token) ------
    if (tid < 128) {
        const int i   = tid >> 4;          // 0..7
        const int sub = tid & 15;          // q = sub, sub+16
        const int tok = i0 + i;
        const int iA  = tok & 15;          // token's row within its A-group
        const int sp  = tok & (S_CONST - 1);
        const int qmx = (S_CONST - 2) - sp;      // max valid q (may be < 0)

        const float* p0 = ps + (size_t)tok * 48 + iA;
        const float* p1 = ps + ((size_t)NTOK + tok) * 48 + iA;

        float v0 = p0[sub]      + p1[sub];
        float v1 = p0[sub + 16] + p1[sub + 16];
        v0 = (sub      <= qmx) ? v0 : -1e9f;
        v1 = (sub + 16 <= qmx) ? v1 : -1e9f;

        float mx = fmaxf(v0, v1);
        #pragma unroll
        for (int d = 1; d < 16; d <<= 1) mx = fmaxf(mx, __shfl_xor(mx, d, 16));

        float e0 = __expf(v0 - mx), e1 = __expf(v1 - mx);
        float sum = e0 + e1;
        #pragma unroll
        for (int d = 1; d < 16; d <<= 1) sum += __shfl_xor(sum, d, 16);

        const bool any = (mx > -5e8f);
        const float inv = any ? (1.0f / sum) : 0.f;

        wm[i * 32 + sub]      = (sub      <= qmx) ? e0 * inv : 0.f;
        wm[i * 32 + sub + 16] = (sub + 16 <= qmx) ? e1 * inv : 0.f;
    }
    __syncthreads();

    // ---- PV: 39-row sliding window, fully unrolled (static indexing) -------
    const int doff = tid * 4;
    float4 acc[TB] = {};
    float4 wv[TB];                                  // rolling weight quads

    #pragma unroll
    for (int rr = 0; rr < TB + 31; ++rr) {          // rows i0+1 .. i0+39
        int r = min(i0 + 1 + rr, NTOK - 1);
        float4 f = *(const float4*)(h + (size_t)r * D + doff);
        #pragma unroll
        for (int t = 0; t < TB; ++t) {
            const int k = rr - t;                   // compile-time constant
            if (k >= 0 && k < 32) {
                if ((k & 3) == 0)
                    wv[t] = *(const float4*)(&wm[t * 32 + k]);
                const float wt = ((k & 3) == 0) ? wv[t].x :
                                 ((k & 3) == 1) ? wv[t].y :
                                 ((k & 3) == 2) ? wv[t].z : wv[t].w;
                acc[t].x += wt * f.x;
                acc[t].y += wt * f.y;
                acc[t].z += wt * f.z;
                acc[t].w += wt * f.w;
            }
        }
    }

    #pragma unroll
    for (int t = 0; t < TB; ++t)
        *(float4*)(out + (size_t)(i0 + t) * D + doff) = acc[t];
}

extern "C" void kernel_launch(void* const* d_in, const int* in_sizes, int n_in,
                              void* d_out, int out_size, void* d_ws, size_t ws_size,
                              hipStream_t stream) {
    const float* h = (const float*)d_in[0];
    float* out = (float*)d_out;
    float* ps = (float*)d_ws;                      // 2*8192*48*4 = 3.1 MiB
    const int ntok = in_sizes[0] / D;              // 8192

    scores_kernel<<<(ntok / G) * 2, 256, 0, stream>>>(h, ps);
    pv_kernel<<<ntok / TB, 256, 0, stream>>>(h, ps, out);
}